// Round 6
// baseline (64.549 us; speedup 1.0000x reference)
//
#include <hip/hip_runtime.h>
#include <hip/hip_bf16.h>
#include <stdint.h>

#define NPTS 131072

typedef __attribute__((ext_vector_type(8))) short bf16x8;
typedef __attribute__((ext_vector_type(4))) float f32x4;
typedef __attribute__((ext_vector_type(8))) unsigned short u16x8;

__device__ inline unsigned short f32_to_bf16(float f) {
    union { __hip_bfloat16 h; unsigned short u; } cv;
    cv.h = __float2bfloat16(f);   // RNE; compiler can pack to v_cvt_pk_bf16_f32
    return cv.u;
}

// Kernel 1 (fused): blocks [0,2048): x NCHW f32 -> xt NHWC bf16, 256 px/block
// in 4 sequential 64-px subtiles (1 KB sequential per channel-plane per block
// for DRAM row locality). Blocks [2048,2066): weight -> fragment-ordered wfrag
// bf16 + zero the 128 B OOB pad.
// wfrag chunk ci = q*8 + half*4 + nn: lane l, elem e holds
//   w[c2=nn*16+(l&15)][cin=half*32+(l>>4)*8+e][q]   (q = dy*3+dx)
__global__ __launch_bounds__(256) void k_prep(const float* __restrict__ x,
                                              unsigned short* __restrict__ xt,
                                              const float* __restrict__ w,
                                              unsigned short* __restrict__ wfrag) {
    if (blockIdx.x >= 2048) {
        int tid = (blockIdx.x - 2048) * 256 + threadIdx.x;  // 0..4607
        int ci = tid >> 6;          // 0..71
        int l  = tid & 63;
        int q    = ci >> 3;
        int half = (ci >> 2) & 1;
        int nn   = ci & 3;
        int c2   = nn * 16 + (l & 15);
        int cin0 = half * 32 + ((l >> 4) << 3);
        u16x8 o;
#pragma unroll
        for (int e = 0; e < 8; ++e)
            o[e] = f32_to_bf16(w[c2 * 576 + (cin0 + e) * 9 + q]);
        *(u16x8*)(wfrag + tid * 8) = o;
        if (blockIdx.x == 2048 && threadIdx.x < 8) {
            u16x8 z = {};
            *(u16x8*)(xt + (size_t)8 * 65536 * 64 + threadIdx.x * 8) = z;
        }
        return;
    }

    __shared__ float tile[64][65];
    int batch   = blockIdx.x >> 8;
    int pixbase = (blockIdx.x & 255) << 8;
    int t = threadIdx.x;
    const float* xb = x + (size_t)batch * 64 * 65536;

    int c0  = t >> 4;           // load: channel group
    int px4 = (t & 15) << 2;    // load: pixel*4 within subtile
    int c8  = (t & 7) << 3;     // store: channel*8
    int pp  = t >> 3;           // store: pixel within subtile

    for (int sub = 0; sub < 4; ++sub) {
        int pix0 = pixbase + (sub << 6);
        if (sub) __syncthreads();   // tile reuse guard
#pragma unroll
        for (int i = 0; i < 4; ++i) {
            int c = c0 + i * 16;
            float4 v = *(const float4*)(xb + (size_t)c * 65536 + pix0 + px4);
            tile[c][px4 + 0] = v.x; tile[c][px4 + 1] = v.y;
            tile[c][px4 + 2] = v.z; tile[c][px4 + 3] = v.w;
        }
        __syncthreads();
#pragma unroll
        for (int h = 0; h < 2; ++h) {
            int pix = pp + h * 32;
            u16x8 o;
#pragma unroll
            for (int i = 0; i < 8; ++i) o[i] = f32_to_bf16(tile[c8 + i][pix]);
            *(u16x8*)(xt + ((size_t)(batch * 65536 + pix0 + pix) * 64 + c8)) = o;
        }
    }
}

// Kernel 3: gather + GEMM. 512 threads = 8 waves; wave owns 32 points (two
// 16-row M-tiles sharing every B-fragment). Half-pixel rolling prefetch keeps
// peak VGPR ~110 (< the __launch_bounds__ 128 cap -> no scratch spills).
// OOB stencil pixels read a zeroed pad. Weights fragment-ordered in LDS.
__global__ __launch_bounds__(512, 4) void k_gather_gemm(
    const unsigned short* __restrict__ xt,
    const unsigned short* __restrict__ wfrag,
    const int* __restrict__ indices,
    const float* __restrict__ bias,
    float* __restrict__ out) {
    __shared__ unsigned short wlds[72 * 512];  // 73728 B

    int t = threadIdx.x;
    int w = t >> 6;
    int l = t & 63;
    int lo = l & 15;
    int hi = l >> 4;

    // Stage weights: 4608 16B-chunks, 9 per thread, fully coalesced
#pragma unroll
    for (int i = 0; i < 9; ++i) {
        int m = t + i * 512;
        *(u16x8*)(&wlds[m * 8]) = *(const u16x8*)(wfrag + m * 8);
    }

    int p0 = blockIdx.x * 256 + w * 32;
    int pA = p0 + lo, pB = p0 + 16 + lo;
    int bA = indices[pA * 3], yA = indices[pA * 3 + 1], xA = indices[pA * 3 + 2];
    int bB = indices[pB * 3], yB = indices[pB * 3 + 1], xB = indices[pB * 3 + 2];

    const uint32_t PADOFF = (uint32_t)8 * 65536 * 128;  // byte offset of zero pad
    uint32_t sub = (uint32_t)(hi << 4);

    auto offq = [&](int b, int y, int x, int q) -> uint32_t {
        int yy = y + (q / 3) - 1;
        int xx = x + (q % 3) - 1;
        bool v = ((unsigned)yy < 256u) & ((unsigned)xx < 256u);
        uint32_t pix = ((uint32_t)b << 16) + ((uint32_t)(yy & 255) << 8) + (uint32_t)(xx & 255);
        return (v ? pix * 128u : PADOFF) + sub;
    };
    auto lda = [&](uint32_t o) -> bf16x8 {
        return (bf16x8)(*(const u16x8*)((const char*)xt + o));
    };

    f32x4 acc[2][4];
#pragma unroll
    for (int m = 0; m < 2; ++m)
#pragma unroll
        for (int nn = 0; nn < 4; ++nn) acc[m][nn] = (f32x4)0.0f;

    __syncthreads();  // wlds ready

    uint32_t oA = offq(bA, yA, xA, 0), oB = offq(bB, yB, xB, 0);
    bf16x8 a00 = lda(oA), a10 = lda(oB);          // current pixel, half0 (t0,t1)
    bf16x8 a01 = lda(oA + 64), a11 = lda(oB + 64); // current pixel, half1

#pragma unroll
    for (int q = 0; q < 9; ++q) {
        bf16x8 n00, n10, m01, m11;
        uint32_t nA = 0, nB = 0;
        if (q < 8) {
            nA = offq(bA, yA, xA, q + 1);
            nB = offq(bB, yB, xB, q + 1);
            n00 = lda(nA); n10 = lda(nB);          // next pixel half0 (16 regs)
        }
        const unsigned short* base = &wlds[q * 4096];  // q's 8 chunks (u16 idx)
#pragma unroll
        for (int nn = 0; nn < 4; ++nn) {
            bf16x8 b0 = *(const bf16x8*)(base + nn * 512 + l * 8);          // half0
            acc[0][nn] = __builtin_amdgcn_mfma_f32_16x16x32_bf16(a00, b0, acc[0][nn], 0, 0, 0);
            acc[1][nn] = __builtin_amdgcn_mfma_f32_16x16x32_bf16(a10, b0, acc[1][nn], 0, 0, 0);
        }
        if (q < 8) { m01 = lda(nA + 64); m11 = lda(nB + 64); }  // next half1 into
                                                                // just-freed space
#pragma unroll
        for (int nn = 0; nn < 4; ++nn) {
            bf16x8 b1 = *(const bf16x8*)(base + 2048 + nn * 512 + l * 8);   // half1
            acc[0][nn] = __builtin_amdgcn_mfma_f32_16x16x32_bf16(a01, b1, acc[0][nn], 0, 0, 0);
            acc[1][nn] = __builtin_amdgcn_mfma_f32_16x16x32_bf16(a11, b1, acc[1][nn], 0, 0, 0);
        }
        if (q < 8) { a00 = n00; a10 = n10; a01 = m01; a11 = m11; }
    }

    // Epilogue: D col = lo (channel within nn-tile), row = hi*4 + r
    int rbase = blockIdx.x * 256 + w * 32 + (hi << 2);
#pragma unroll
    for (int nn = 0; nn < 4; ++nn) {
        float bv = bias[nn * 16 + lo];
#pragma unroll
        for (int m = 0; m < 2; ++m) {
#pragma unroll
            for (int r = 0; r < 4; ++r) {
                out[(size_t)(rbase + m * 16 + r) * 64 + nn * 16 + lo] = acc[m][nn][r] + bv;
            }
        }
    }
}

// Fallback if workspace too small: naive direct conv (correct, slow)
__global__ void k_naive(const float* __restrict__ x, const int* __restrict__ idx,
                        const float* __restrict__ w, const float* __restrict__ bias,
                        float* __restrict__ out) {
    int i = blockIdx.x * 256 + threadIdx.x;
    if (i >= NPTS * 64) return;
    int p = i >> 6, c2 = i & 63;
    int b = idx[p * 3], yi = idx[p * 3 + 1], xi = idx[p * 3 + 2];
    float acc = bias[c2];
    for (int c = 0; c < 64; ++c) {
        const float* xp = x + ((size_t)(b * 64 + c) << 16);
        const float* wp = w + (c2 * 64 + c) * 9;
        for (int dy = 0; dy < 3; ++dy) {
            int yy = yi + dy - 1;
            if ((unsigned)yy >= 256u) continue;
            for (int dx = 0; dx < 3; ++dx) {
                int xx = xi + dx - 1;
                if ((unsigned)xx >= 256u) continue;
                acc += xp[(yy << 8) + xx] * wp[dy * 3 + dx];
            }
        }
    }
    out[i] = acc;
}

extern "C" void kernel_launch(void* const* d_in, const int* in_sizes, int n_in,
                              void* d_out, int out_size, void* d_ws, size_t ws_size,
                              hipStream_t stream) {
    const float* x       = (const float*)d_in[0];
    const int*   indices = (const int*)d_in[1];
    const float* weight  = (const float*)d_in[2];
    const float* bias    = (const float*)d_in[3];
    float* out = (float*)d_out;

    size_t xt_bytes = (size_t)8 * 65536 * 64 * 2 + 128;   // incl. 128 B zero pad
    size_t need = xt_bytes + (size_t)72 * 1024;           // + wfrag
    if (ws_size < need) {
        k_naive<<<(NPTS * 64 + 255) / 256, 256, 0, stream>>>(x, indices, weight, bias, out);
        return;
    }
    unsigned short* xt    = (unsigned short*)d_ws;
    unsigned short* wfrag = (unsigned short*)((char*)d_ws + xt_bytes);

    k_prep<<<2048 + 18, 256, 0, stream>>>(x, xt, weight, wfrag);
    k_gather_gemm<<<NPTS / 256, 512, 0, stream>>>(xt, wfrag, indices, bias, out);
}